// Round 1
// baseline (223.909 us; speedup 1.0000x reference)
//
#include <hip/hip_runtime.h>
#include <math.h>

#define NROWS 65536
#define DDIM  64
#define KCB   1024

// ---------------------------------------------------------------------------
// Kernel 1: C2[j] = ||W_j||^2 via numpy pairwise-sum emulation (n=64: 8 accs).
// ---------------------------------------------------------------------------
__global__ void vq_c2_kernel(const float* __restrict__ W, float* __restrict__ C2) {
    int j = blockIdx.x * blockDim.x + threadIdx.x;
    if (j >= KCB) return;
    const float* w = W + (size_t)j * DDIM;
    float r[8];
#pragma unroll
    for (int m = 0; m < 8; ++m) r[m] = __fmul_rn(w[m], w[m]);
#pragma unroll
    for (int i = 8; i < 64; i += 8) {
#pragma unroll
        for (int m = 0; m < 8; ++m)
            r[m] = __fadd_rn(r[m], __fmul_rn(w[i + m], w[i + m]));
    }
    float res = __fadd_rn(
        __fadd_rn(__fadd_rn(r[0], r[1]), __fadd_rn(r[2], r[3])),
        __fadd_rn(__fadd_rn(r[4], r[5]), __fadd_rn(r[6], r[7])));
    C2[j] = res;
}

// ---------------------------------------------------------------------------
// Kernel 2: main argmin. Block = 256 threads = 4 waves. Each block owns 64
// rows; lane l handles row block*64+l; wave s scans codes [s*256, s*256+256).
// W rows are wave-uniform -> scalar loads (L2-resident, 256 KB total).
// dist emulates numpy fp32: (L2 - 2*CL) + C2, CL = sequential fp32 FMA chain.
// First-index tie-break via strict < and ordered combine.
// ---------------------------------------------------------------------------
__global__ void __launch_bounds__(256, 4)
vq_main_kernel(const float* __restrict__ x, const float* __restrict__ W,
               const float* __restrict__ C2, int* __restrict__ cls_i,
               float* __restrict__ cls_f) {
    __shared__ float s_bd[4][64];
    __shared__ int   s_bi[4][64];

    const int lane = threadIdx.x & 63;
    const int s    = __builtin_amdgcn_readfirstlane(threadIdx.x >> 6);
    const int row  = blockIdx.x * 64 + lane;

    // Load this row of x into registers (16 x float4).
    const float* xr = x + (size_t)row * DDIM;
    float xv[64];
#pragma unroll
    for (int k = 0; k < 64; k += 4) {
        float4 v = *(const float4*)(xr + k);
        xv[k] = v.x; xv[k + 1] = v.y; xv[k + 2] = v.z; xv[k + 3] = v.w;
    }

    // L2 = numpy pairwise sum of x*x (n=64).
    float r[8];
#pragma unroll
    for (int m = 0; m < 8; ++m) r[m] = __fmul_rn(xv[m], xv[m]);
#pragma unroll
    for (int i = 8; i < 64; i += 8) {
#pragma unroll
        for (int m = 0; m < 8; ++m)
            r[m] = __fadd_rn(r[m], __fmul_rn(xv[i + m], xv[i + m]));
    }
    const float L2 = __fadd_rn(
        __fadd_rn(__fadd_rn(r[0], r[1]), __fadd_rn(r[2], r[3])),
        __fadd_rn(__fadd_rn(r[4], r[5]), __fadd_rn(r[6], r[7])));

    float best = INFINITY;
    int   bidx = 0;
    const int j0 = s * 256;
    for (int jj = 0; jj < 256; ++jj) {
        const int j = j0 + jj;
        const float* wr = W + (size_t)j * DDIM;  // wave-uniform -> s_load
        float acc = 0.0f;
#pragma unroll
        for (int k = 0; k < 64; ++k)
            acc = __builtin_fmaf(xv[k], wr[k], acc);
        const float dist = __fadd_rn(__fsub_rn(L2, __fmul_rn(2.0f, acc)), C2[j]);
        if (dist < best) { best = dist; bidx = j; }  // strict <: keep lowest j
    }

    s_bd[s][lane] = best;
    s_bi[s][lane] = bidx;
    __syncthreads();

    if (s == 0) {
        float b  = s_bd[0][lane];
        int   bi = s_bi[0][lane];
#pragma unroll
        for (int t = 1; t < 4; ++t) {
            const float d = s_bd[t][lane];
            if (d < b) { b = d; bi = s_bi[t][lane]; }  // ascending j-ranges
        }
        cls_i[row] = bi;
        cls_f[row] = (float)bi;  // harness reads indices as fp32
    }
}

// ---------------------------------------------------------------------------
// Kernel 3: gather quantized = W[closest]. 16 threads/row, float4 each.
// ---------------------------------------------------------------------------
__global__ void vq_gather_kernel(const float* __restrict__ W,
                                 const int* __restrict__ cls,
                                 float* __restrict__ outq) {
    const int t = blockIdx.x * blockDim.x + threadIdx.x;
    const int i = t >> 4;
    const int q = t & 15;
    const int j = cls[i];
    const float4 v = *(const float4*)(W + (size_t)j * DDIM + q * 4);
    *(float4*)(outq + (size_t)i * DDIM + q * 4) = v;
}

extern "C" void kernel_launch(void* const* d_in, const int* in_sizes, int n_in,
                              void* d_out, int out_size, void* d_ws, size_t ws_size,
                              hipStream_t stream) {
    const float* x = (const float*)d_in[0];
    const float* W = (const float*)d_in[1];

    float* outq = (float*)d_out;                        // N*D quantized
    float* outi = (float*)d_out + (size_t)NROWS * DDIM; // N indices as float

    float* C2  = (float*)d_ws;                          // 4 KB
    int*   cls = (int*)((char*)d_ws + 4096);            // 256 KB

    hipLaunchKernelGGL(vq_c2_kernel, dim3(KCB / 256), dim3(256), 0, stream, W, C2);
    hipLaunchKernelGGL(vq_main_kernel, dim3(NROWS / 64), dim3(256), 0, stream,
                       x, W, C2, cls, outi);
    hipLaunchKernelGGL(vq_gather_kernel, dim3((NROWS * 16) / 256), dim3(256), 0,
                       stream, W, cls, outq);
}